// Round 1
// 772.349 us; speedup vs baseline: 1.1636x; 1.1636x over previous
//
#include <hip/hip_runtime.h>
#include <math.h>

#define NEG_SLOPE 0.2f
#define EPS_DEN 1e-16f

__device__ __forceinline__ float leaky(float v) { return v > 0.f ? v : NEG_SLOPE * v; }

typedef __attribute__((ext_vector_type(8))) short bf16x8;
typedef __attribute__((ext_vector_type(4))) float f32x4;

__device__ __forceinline__ unsigned bf16rne(float f) {
    unsigned u = __float_as_uint(f);
    return (u + 0x7FFFu + ((u >> 16) & 1u)) >> 16;
}
__device__ __forceinline__ unsigned pack2(float a, float b) {
    return bf16rne(a) | (bf16rne(b) << 16);
}
__device__ __forceinline__ float bfu(unsigned short u) {
    return __uint_as_float(((unsigned)u) << 16);
}

// ---------- GEMM1 (MFMA): h1b[N,64](bf16) = x[N,512] @ W1[512,64] ----------
__global__ __launch_bounds__(256) void gemm1_mfma(
    const float* __restrict__ x, const float* __restrict__ W1,
    unsigned short* __restrict__ h1b, int N)
{
    __shared__ __align__(16) unsigned short As[128 * 40];
    __shared__ __align__(16) unsigned short Bs[64 * 40];

    const int t = threadIdx.x;
    const int w = t >> 6;
    const int lane = t & 63;
    const int m16 = lane & 15;
    const int quad = lane >> 4;
    const int rowBase = blockIdx.x * 128;

    f32x4 acc[2][4];
#pragma unroll
    for (int i = 0; i < 2; ++i)
#pragma unroll
        for (int j = 0; j < 4; ++j) acc[i][j] = (f32x4){0.f, 0.f, 0.f, 0.f};

    const float4* x4 = (const float4*)x;

#pragma unroll 1
    for (int chunk = 0; chunk < 16; ++chunk) {
        const int k0 = chunk * 32;
#pragma unroll
        for (int r = 0; r < 4; ++r) {
            int e = t + r * 256;
            int row = e >> 3;
            int kg = e & 7;
            int grow = rowBase + row;
            float4 v = make_float4(0.f, 0.f, 0.f, 0.f);
            if (grow < N) v = x4[(size_t)grow * 128 + (k0 >> 2) + kg];
            uint2 pk = make_uint2(pack2(v.x, v.y), pack2(v.z, v.w));
            *(uint2*)&As[row * 40 + kg * 4] = pk;
        }
        {
            int c = lane;
            int jb = w * 8;
            float f[8];
#pragma unroll
            for (int j = 0; j < 8; ++j) f[j] = W1[(size_t)(k0 + jb + j) * 64 + c];
            uint4 pk;
            pk.x = pack2(f[0], f[1]); pk.y = pack2(f[2], f[3]);
            pk.z = pack2(f[4], f[5]); pk.w = pack2(f[6], f[7]);
            *(uint4*)&Bs[c * 40 + jb] = pk;
        }
        __syncthreads();
        bf16x8 a0 = *(const bf16x8*)&As[(w * 32 + m16) * 40 + quad * 8];
        bf16x8 a1 = *(const bf16x8*)&As[(w * 32 + 16 + m16) * 40 + quad * 8];
#pragma unroll
        for (int j = 0; j < 4; ++j) {
            bf16x8 b = *(const bf16x8*)&Bs[(j * 16 + m16) * 40 + quad * 8];
            acc[0][j] = __builtin_amdgcn_mfma_f32_16x16x32_bf16(a0, b, acc[0][j], 0, 0, 0);
            acc[1][j] = __builtin_amdgcn_mfma_f32_16x16x32_bf16(a1, b, acc[1][j], 0, 0, 0);
        }
        __syncthreads();
    }

#pragma unroll
    for (int i = 0; i < 2; ++i)
#pragma unroll
        for (int reg = 0; reg < 4; ++reg) {
            int r = rowBase + w * 32 + i * 16 + quad * 4 + reg;
            if (r < N) {
#pragma unroll
                for (int j = 0; j < 4; ++j)
                    h1b[(size_t)r * 64 + j * 16 + m16] = (unsigned short)bf16rne(acc[i][j][reg]);
            }
        }
}

// ---------- attention dots for L1 (reads bf16 h1) ----------
__global__ __launch_bounds__(256) void att1_kernel(
    const unsigned short* __restrict__ h1b, const float* __restrict__ att_src,
    const float* __restrict__ att_dst, float* __restrict__ a_src,
    float* __restrict__ a_dst, int N)
{
    int g = blockIdx.x * 256 + threadIdx.x;
    int row = g >> 3, h = g & 7;
    if (row >= N) return;
    uint4 pk = *(const uint4*)(h1b + (size_t)row * 64 + h * 8);
    float v[8];
    v[0] = __uint_as_float(pk.x << 16); v[1] = __uint_as_float(pk.x & 0xFFFF0000u);
    v[2] = __uint_as_float(pk.y << 16); v[3] = __uint_as_float(pk.y & 0xFFFF0000u);
    v[4] = __uint_as_float(pk.z << 16); v[5] = __uint_as_float(pk.z & 0xFFFF0000u);
    v[6] = __uint_as_float(pk.w << 16); v[7] = __uint_as_float(pk.w & 0xFFFF0000u);
    float ps = 0.f, pd = 0.f;
#pragma unroll
    for (int c = 0; c < 8; ++c) {
        ps += v[c] * att_src[h * 8 + c];
        pd += v[c] * att_dst[h * 8 + c];
    }
    a_src[(size_t)row * 8 + h] = ps;
    a_dst[(size_t)row * 8 + h] = pd;
}

// ---------- CSR build ----------
__global__ __launch_bounds__(256) void deg_kernel(
    const int* __restrict__ ei, unsigned* __restrict__ deg, int E, int Etot)
{
    int idx = blockIdx.x * blockDim.x + threadIdx.x;
    if (idx >= Etot) return;
    int d = (idx < E) ? ei[E + idx] : (idx - E);
    atomicAdd(&deg[d], 1u);
}

__global__ __launch_bounds__(256) void scanA_kernel(
    const unsigned* __restrict__ deg, unsigned* __restrict__ loc,
    unsigned* __restrict__ bsum, int N)
{
    __shared__ unsigned sh[256];
    int i = blockIdx.x * 256 + threadIdx.x;
    unsigned v = (i < N) ? deg[i] : 0u;
    sh[threadIdx.x] = v;
    __syncthreads();
    for (int off = 1; off < 256; off <<= 1) {
        unsigned u = (threadIdx.x >= (unsigned)off) ? sh[threadIdx.x - off] : 0u;
        __syncthreads();
        sh[threadIdx.x] += u;
        __syncthreads();
    }
    if (i < N) loc[i] = sh[threadIdx.x] - v;
    if (threadIdx.x == 255) bsum[blockIdx.x] = sh[255];
}

__global__ __launch_bounds__(1024) void scanB_kernel(unsigned* __restrict__ bsum, int nb)
{
    __shared__ unsigned sh[1024];
    int t = threadIdx.x;
    unsigned carry = 0;
    for (int base = 0; base < nb; base += 1024) {
        int i = base + t;
        unsigned v = (i < nb) ? bsum[i] : 0u;
        sh[t] = v;
        __syncthreads();
        for (int off = 1; off < 1024; off <<= 1) {
            unsigned u = (t >= off) ? sh[t - off] : 0u;
            __syncthreads();
            sh[t] += u;
            __syncthreads();
        }
        unsigned incl = sh[t];
        unsigned tot  = sh[1023];
        __syncthreads();
        if (i < nb) bsum[i] = incl - v + carry;
        carry += tot;
        __syncthreads();
    }
}

__global__ __launch_bounds__(256) void scanC_kernel(
    const unsigned* __restrict__ loc, const unsigned* __restrict__ bsum,
    unsigned* __restrict__ rowstart, unsigned* __restrict__ cursor, int N, int Etot)
{
    int i = blockIdx.x * 256 + threadIdx.x;
    if (i >= N) return;
    unsigned r = loc[i] + bsum[blockIdx.x];
    rowstart[i] = r;
    cursor[i] = r;
    if (i == 0) rowstart[N] = (unsigned)Etot;
}

__global__ __launch_bounds__(256) void scatter_kernel(
    const int* __restrict__ ei, unsigned* __restrict__ cursor,
    int* __restrict__ csr_src, int E, int Etot)
{
    int idx = blockIdx.x * blockDim.x + threadIdx.x;
    if (idx >= Etot) return;
    int s, d;
    if (idx < E) { s = ei[idx]; d = ei[E + idx]; } else { s = d = idx - E; }
    unsigned pos = atomicAdd(&cursor[d], 1u);
    csr_src[pos] = s;
}

// ---------- L1 fused aggregate: wave per dst, online exp + weighted sum ----------
// p = exp(leaky(a_src[s] + a_dst[g])) computed inline (no max pass: logits are
// ~N(0, 3.6), max over 12.8M samples ~ 11 -> exp stays < ~5e4, fp32-safe).
__global__ __launch_bounds__(256) void aggr1_kernel(
    const unsigned* __restrict__ rowstart, const int* __restrict__ csr_src,
    const float* __restrict__ a_src, const float* __restrict__ a_dst,
    const unsigned short* __restrict__ h1b, const float* __restrict__ b1,
    float* __restrict__ h2, int N)
{
    int g = blockIdx.x * 4 + (threadIdx.x >> 6);
    int lane = threadIdx.x & 63;
    if (g >= N) return;
    int h = lane >> 3;
    float ad = a_dst[(size_t)g * 8 + h];
    unsigned k0 = rowstart[g], k1 = rowstart[g + 1];
    float acc0 = 0.f, acc1 = 0.f, acc2 = 0.f, acc3 = 0.f;
    float dn0 = 0.f, dn1 = 0.f, dn2 = 0.f, dn3 = 0.f;
    unsigned k = k0;
    for (; k + 4 <= k1; k += 4) {
        int s0 = csr_src[k],     s1 = csr_src[k + 1];
        int s2 = csr_src[k + 2], s3 = csr_src[k + 3];
        float p0 = __expf(leaky(a_src[(size_t)s0 * 8 + h] + ad));
        float p1 = __expf(leaky(a_src[(size_t)s1 * 8 + h] + ad));
        float p2 = __expf(leaky(a_src[(size_t)s2 * 8 + h] + ad));
        float p3 = __expf(leaky(a_src[(size_t)s3 * 8 + h] + ad));
        acc0 += p0 * bfu(h1b[(size_t)s0 * 64 + lane]); dn0 += p0;
        acc1 += p1 * bfu(h1b[(size_t)s1 * 64 + lane]); dn1 += p1;
        acc2 += p2 * bfu(h1b[(size_t)s2 * 64 + lane]); dn2 += p2;
        acc3 += p3 * bfu(h1b[(size_t)s3 * 64 + lane]); dn3 += p3;
    }
    for (; k < k1; ++k) {
        int s0 = csr_src[k];
        float p0 = __expf(leaky(a_src[(size_t)s0 * 8 + h] + ad));
        acc0 += p0 * bfu(h1b[(size_t)s0 * 64 + lane]); dn0 += p0;
    }
    float den = (dn0 + dn1) + (dn2 + dn3);
    float acc = (acc0 + acc1) + (acc2 + acc3);
    float v = acc / (den + EPS_DEN) + b1[lane];
    h2[(size_t)g * 64 + lane] = v > 0.f ? v : 0.f;
}

// ---------- GEMM2 + attention dots: h3b[N,40](bf16) ----------
__global__ __launch_bounds__(256) void gemm2_kernel(
    const float* __restrict__ h2, const float* __restrict__ W2,
    const float* __restrict__ att_src2, const float* __restrict__ att_dst2,
    unsigned short* __restrict__ h3b, float* __restrict__ a_src, float* __restrict__ a_dst, int N)
{
    __shared__ float Wl[64 * 40];
    int t = threadIdx.x;
    for (int i = t; i < 64 * 40; i += 256) Wl[i] = W2[i];
    __syncthreads();
    int lane = t & 63, wy = t >> 6;
    int row = blockIdx.x * 4 + wy;
    if (row >= N) return;
    float acc = 0.f;
    const float* hr = h2 + (size_t)row * 64;
    if (lane < 40) {
#pragma unroll 8
        for (int k = 0; k < 64; ++k) acc += hr[k] * Wl[k * 40 + lane];
        h3b[(size_t)row * 40 + lane] = (unsigned short)bf16rne(acc);
    }
    float ps = (lane < 40) ? acc * att_src2[lane] : 0.f;
    float pd = (lane < 40) ? acc * att_dst2[lane] : 0.f;
#pragma unroll
    for (int off = 32; off; off >>= 1) { ps += __shfl_down(ps, off); pd += __shfl_down(pd, off); }
    if (lane == 0) { a_src[row] = ps; a_dst[row] = pd; }
}

// ---------- L2 fused aggregate: wave per dst, online exp + bias + log_softmax ----------
__global__ __launch_bounds__(256) void aggr2_kernel(
    const unsigned* __restrict__ rowstart, const int* __restrict__ csr_src,
    const float* __restrict__ a_src, const float* __restrict__ a_dst,
    const unsigned short* __restrict__ h3b, const float* __restrict__ b2,
    float* __restrict__ y, int N)
{
    int g = blockIdx.x * 4 + (threadIdx.x >> 6);
    int lane = threadIdx.x & 63;
    if (g >= N) return;
    float ad = a_dst[g];
    unsigned k0 = rowstart[g], k1 = rowstart[g + 1];
    float acc0 = 0.f, acc1 = 0.f, acc2 = 0.f, acc3 = 0.f;
    float dn0 = 0.f, dn1 = 0.f, dn2 = 0.f, dn3 = 0.f;
    unsigned k = k0;
    for (; k + 4 <= k1; k += 4) {
        int s0 = csr_src[k],     s1 = csr_src[k + 1];
        int s2 = csr_src[k + 2], s3 = csr_src[k + 3];
        float p0 = __expf(leaky(a_src[s0] + ad));
        float p1 = __expf(leaky(a_src[s1] + ad));
        float p2 = __expf(leaky(a_src[s2] + ad));
        float p3 = __expf(leaky(a_src[s3] + ad));
        float hv0 = (lane < 40) ? bfu(h3b[(size_t)s0 * 40 + lane]) : 0.f;
        float hv1 = (lane < 40) ? bfu(h3b[(size_t)s1 * 40 + lane]) : 0.f;
        float hv2 = (lane < 40) ? bfu(h3b[(size_t)s2 * 40 + lane]) : 0.f;
        float hv3 = (lane < 40) ? bfu(h3b[(size_t)s3 * 40 + lane]) : 0.f;
        acc0 += p0 * hv0; dn0 += p0;
        acc1 += p1 * hv1; dn1 += p1;
        acc2 += p2 * hv2; dn2 += p2;
        acc3 += p3 * hv3; dn3 += p3;
    }
    for (; k < k1; ++k) {
        int s0 = csr_src[k];
        float p0 = __expf(leaky(a_src[s0] + ad));
        float hv0 = (lane < 40) ? bfu(h3b[(size_t)s0 * 40 + lane]) : 0.f;
        acc0 += p0 * hv0; dn0 += p0;
    }
    float den = (dn0 + dn1) + (dn2 + dn3);
    float acc = (acc0 + acc1) + (acc2 + acc3);
    float v = (lane < 40) ? (acc / (den + EPS_DEN) + b2[lane]) : -INFINITY;
    float mx = v;
#pragma unroll
    for (int off = 32; off; off >>= 1) mx = fmaxf(mx, __shfl_down(mx, off));
    mx = __shfl(mx, 0);
    float ex = (lane < 40) ? expf(v - mx) : 0.f;
    float ss = ex;
#pragma unroll
    for (int off = 32; off; off >>= 1) ss += __shfl_down(ss, off);
    ss = __shfl(ss, 0);
    if (lane < 40) y[(size_t)g * 40 + lane] = v - mx - logf(ss);
}

// ---------- launch ----------
extern "C" void kernel_launch(void* const* d_in, const int* in_sizes, int n_in,
                              void* d_out, int out_size, void* d_ws, size_t ws_size,
                              hipStream_t stream)
{
    const float* x        = (const float*)d_in[0];
    const int*   ei       = (const int*)d_in[1];
    const float* W1       = (const float*)d_in[2];
    const float* att_src1 = (const float*)d_in[3];
    const float* att_dst1 = (const float*)d_in[4];
    const float* b1       = (const float*)d_in[5];
    const float* W2       = (const float*)d_in[6];
    const float* att_src2 = (const float*)d_in[7];
    const float* att_dst2 = (const float*)d_in[8];
    const float* b2       = (const float*)d_in[9];
    float* y = (float*)d_out;

    int N = in_sizes[0] / 512;
    int E = in_sizes[1] / 2;
    int Etot = E + N;
    int nb = (N + 255) / 256;

    char* p = (char*)d_ws;
    unsigned short* h1b = (unsigned short*)p; p += (size_t)N * 64 * 2;
    float* a_src1a  = (float*)p;   p += (size_t)N * 8 * 4;
    float* a_dst1a  = (float*)p;   p += (size_t)N * 8 * 4;
    float* h2       = (float*)p;   p += (size_t)N * 64 * 4;
    unsigned short* h3b = (unsigned short*)p; p += (size_t)N * 40 * 2;
    float* a_src2a  = (float*)p;   p += (size_t)N * 4;
    float* a_dst2a  = (float*)p;   p += (size_t)N * 4;
    unsigned* deg   = (unsigned*)p; p += (size_t)N * 4;
    unsigned* loc   = (unsigned*)p; p += (size_t)N * 4;
    unsigned* bsum  = (unsigned*)p; p += (size_t)nb * 4;
    unsigned* rowstart = (unsigned*)p; p += (size_t)(N + 1) * 4;
    unsigned* cursor   = (unsigned*)p; p += (size_t)N * 4;
    int* csr_src    = (int*)p;     p += (size_t)Etot * 4;

    hipMemsetAsync(deg, 0, (size_t)N * 4, stream);

    // GEMM1 (MFMA) then attention logits
    gemm1_mfma<<<(N + 127) / 128, 256, 0, stream>>>(x, W1, h1b, N);
    att1_kernel<<<(N * 8 + 255) / 256, 256, 0, stream>>>(h1b, att_src1, att_dst1, a_src1a, a_dst1a, N);

    // CSR build (shared by both layers)
    deg_kernel<<<(Etot + 255) / 256, 256, 0, stream>>>(ei, deg, E, Etot);
    scanA_kernel<<<nb, 256, 0, stream>>>(deg, loc, bsum, N);
    scanB_kernel<<<1, 1024, 0, stream>>>(bsum, nb);
    scanC_kernel<<<nb, 256, 0, stream>>>(loc, bsum, rowstart, cursor, N, Etot);
    scatter_kernel<<<(Etot + 255) / 256, 256, 0, stream>>>(ei, cursor, csr_src, E, Etot);

    // L1: fused softmax + aggregate + bias + relu (no max pass, no alpha array)
    aggr1_kernel<<<(N + 3) / 4, 256, 0, stream>>>(rowstart, csr_src, a_src1a, a_dst1a, h1b, b1, h2, N);

    // GEMM2 + attention logits
    gemm2_kernel<<<(N + 3) / 4, 256, 0, stream>>>(h2, W2, att_src2, att_dst2, h3b, a_src2a, a_dst2a, N);

    // L2: fused softmax + aggregate + bias + log_softmax
    aggr2_kernel<<<(N + 3) / 4, 256, 0, stream>>>(rowstart, csr_src, a_src2a, a_dst2a, h3b, b2, y, N);
}

// Round 2
// 692.356 us; speedup vs baseline: 1.2980x; 1.1155x over previous
//
#include <hip/hip_runtime.h>
#include <math.h>

#define NEG_SLOPE 0.2f
#define EPS_DEN 1e-16f

__device__ __forceinline__ float leaky(float v) { return v > 0.f ? v : NEG_SLOPE * v; }

typedef __attribute__((ext_vector_type(8))) short bf16x8;
typedef __attribute__((ext_vector_type(4))) float f32x4;

__device__ __forceinline__ unsigned bf16rne(float f) {
    unsigned u = __float_as_uint(f);
    return (u + 0x7FFFu + ((u >> 16) & 1u)) >> 16;
}
// HW packed f32->bf16 RNE convert: 1 instr instead of ~10
__device__ __forceinline__ unsigned pack2(float a, float b) {
    unsigned r;
    asm("v_cvt_pk_bf16_f32 %0, %1, %2" : "=v"(r) : "v"(a), "v"(b));
    return r;
}
__device__ __forceinline__ float bfu(unsigned short u) {
    return __uint_as_float(((unsigned)u) << 16);
}

// ---------- GEMM1 (MFMA): h1b[N,64](bf16) = x[N,512] @ W1[512,64] ----------
__global__ __launch_bounds__(256) void gemm1_mfma(
    const float* __restrict__ x, const float* __restrict__ W1,
    unsigned short* __restrict__ h1b, int N)
{
    __shared__ __align__(16) unsigned short As[128 * 40];
    __shared__ __align__(16) unsigned short Bs[64 * 40];

    const int t = threadIdx.x;
    const int w = t >> 6;
    const int lane = t & 63;
    const int m16 = lane & 15;
    const int quad = lane >> 4;
    const int rowBase = blockIdx.x * 128;

    f32x4 acc[2][4];
#pragma unroll
    for (int i = 0; i < 2; ++i)
#pragma unroll
        for (int j = 0; j < 4; ++j) acc[i][j] = (f32x4){0.f, 0.f, 0.f, 0.f};

    const float4* x4 = (const float4*)x;

#pragma unroll 1
    for (int chunk = 0; chunk < 16; ++chunk) {
        const int k0 = chunk * 32;
#pragma unroll
        for (int r = 0; r < 4; ++r) {
            int e = t + r * 256;
            int row = e >> 3;
            int kg = e & 7;
            int grow = rowBase + row;
            float4 v = make_float4(0.f, 0.f, 0.f, 0.f);
            if (grow < N) v = x4[(size_t)grow * 128 + (k0 >> 2) + kg];
            uint2 pk = make_uint2(pack2(v.x, v.y), pack2(v.z, v.w));
            *(uint2*)&As[row * 40 + kg * 4] = pk;
        }
        {
            int c = lane;
            int jb = w * 8;
            float f[8];
#pragma unroll
            for (int j = 0; j < 8; ++j) f[j] = W1[(size_t)(k0 + jb + j) * 64 + c];
            uint4 pk;
            pk.x = pack2(f[0], f[1]); pk.y = pack2(f[2], f[3]);
            pk.z = pack2(f[4], f[5]); pk.w = pack2(f[6], f[7]);
            *(uint4*)&Bs[c * 40 + jb] = pk;
        }
        __syncthreads();
        bf16x8 a0 = *(const bf16x8*)&As[(w * 32 + m16) * 40 + quad * 8];
        bf16x8 a1 = *(const bf16x8*)&As[(w * 32 + 16 + m16) * 40 + quad * 8];
#pragma unroll
        for (int j = 0; j < 4; ++j) {
            bf16x8 b = *(const bf16x8*)&Bs[(j * 16 + m16) * 40 + quad * 8];
            acc[0][j] = __builtin_amdgcn_mfma_f32_16x16x32_bf16(a0, b, acc[0][j], 0, 0, 0);
            acc[1][j] = __builtin_amdgcn_mfma_f32_16x16x32_bf16(a1, b, acc[1][j], 0, 0, 0);
        }
        __syncthreads();
    }

#pragma unroll
    for (int i = 0; i < 2; ++i)
#pragma unroll
        for (int reg = 0; reg < 4; ++reg) {
            int r = rowBase + w * 32 + i * 16 + quad * 4 + reg;
            if (r < N) {
#pragma unroll
                for (int j = 0; j < 4; ++j)
                    h1b[(size_t)r * 64 + j * 16 + m16] = (unsigned short)bf16rne(acc[i][j][reg]);
            }
        }
}

// ---------- attention dots for L1 (reads bf16 h1) ----------
__global__ __launch_bounds__(256) void att1_kernel(
    const unsigned short* __restrict__ h1b, const float* __restrict__ att_src,
    const float* __restrict__ att_dst, float* __restrict__ a_src,
    float* __restrict__ a_dst, int N)
{
    int g = blockIdx.x * 256 + threadIdx.x;
    int row = g >> 3, h = g & 7;
    if (row >= N) return;
    uint4 pk = *(const uint4*)(h1b + (size_t)row * 64 + h * 8);
    float v[8];
    v[0] = __uint_as_float(pk.x << 16); v[1] = __uint_as_float(pk.x & 0xFFFF0000u);
    v[2] = __uint_as_float(pk.y << 16); v[3] = __uint_as_float(pk.y & 0xFFFF0000u);
    v[4] = __uint_as_float(pk.z << 16); v[5] = __uint_as_float(pk.z & 0xFFFF0000u);
    v[6] = __uint_as_float(pk.w << 16); v[7] = __uint_as_float(pk.w & 0xFFFF0000u);
    float ps = 0.f, pd = 0.f;
#pragma unroll
    for (int c = 0; c < 8; ++c) {
        ps += v[c] * att_src[h * 8 + c];
        pd += v[c] * att_dst[h * 8 + c];
    }
    a_src[(size_t)row * 8 + h] = ps;
    a_dst[(size_t)row * 8 + h] = pd;
}

// ---------- CSR build ----------
__global__ __launch_bounds__(256) void deg_kernel(
    const int* __restrict__ ei, unsigned* __restrict__ deg, int E, int Etot)
{
    int idx = blockIdx.x * blockDim.x + threadIdx.x;
    if (idx >= Etot) return;
    int d = (idx < E) ? ei[E + idx] : (idx - E);
    atomicAdd(&deg[d], 1u);
}

__global__ __launch_bounds__(256) void scanA_kernel(
    const unsigned* __restrict__ deg, unsigned* __restrict__ loc,
    unsigned* __restrict__ bsum, int N)
{
    __shared__ unsigned sh[256];
    int i = blockIdx.x * 256 + threadIdx.x;
    unsigned v = (i < N) ? deg[i] : 0u;
    sh[threadIdx.x] = v;
    __syncthreads();
    for (int off = 1; off < 256; off <<= 1) {
        unsigned u = (threadIdx.x >= (unsigned)off) ? sh[threadIdx.x - off] : 0u;
        __syncthreads();
        sh[threadIdx.x] += u;
        __syncthreads();
    }
    if (i < N) loc[i] = sh[threadIdx.x] - v;
    if (threadIdx.x == 255) bsum[blockIdx.x] = sh[255];
}

__global__ __launch_bounds__(1024) void scanB_kernel(unsigned* __restrict__ bsum, int nb)
{
    __shared__ unsigned sh[1024];
    int t = threadIdx.x;
    unsigned carry = 0;
    for (int base = 0; base < nb; base += 1024) {
        int i = base + t;
        unsigned v = (i < nb) ? bsum[i] : 0u;
        sh[t] = v;
        __syncthreads();
        for (int off = 1; off < 1024; off <<= 1) {
            unsigned u = (t >= off) ? sh[t - off] : 0u;
            __syncthreads();
            sh[t] += u;
            __syncthreads();
        }
        unsigned incl = sh[t];
        unsigned tot  = sh[1023];
        __syncthreads();
        if (i < nb) bsum[i] = incl - v + carry;
        carry += tot;
        __syncthreads();
    }
}

__global__ __launch_bounds__(256) void scanC_kernel(
    const unsigned* __restrict__ loc, const unsigned* __restrict__ bsum,
    unsigned* __restrict__ rowstart, unsigned* __restrict__ cursor, int N, int Etot)
{
    int i = blockIdx.x * 256 + threadIdx.x;
    if (i >= N) return;
    unsigned r = loc[i] + bsum[blockIdx.x];
    rowstart[i] = r;
    cursor[i] = r;
    if (i == 0) rowstart[N] = (unsigned)Etot;
}

// ---------- XCD-sliced scatter: slice sigma of dst-range handled only by blocks
// with blockIdx%8==sigma (dispatch round-robins blocks over the 8 XCDs), so each
// slice's ~850KB csr region stays resident in ONE XCD's L2 and lines collect all
// their writes before writeback (kills the 16x write amplification). ----------
__global__ __launch_bounds__(256) void scatter_kernel(
    const int* __restrict__ ei, unsigned* __restrict__ cursor,
    int* __restrict__ csr_src, int E, int Etot, int sliceW)
{
    int slice = blockIdx.x & 7;
    int idx = (blockIdx.x >> 3) * 256 + threadIdx.x;
    if (idx >= Etot) return;
    int d = (idx < E) ? ei[E + idx] : (idx - E);
    int lo = slice * sliceW;
    if (d < lo || d >= lo + sliceW) return;
    int s = (idx < E) ? ei[idx] : d;
    unsigned pos = atomicAdd(&cursor[d], 1u);
    csr_src[pos] = s;
}

// ---------- L1 fused aggregate: wave per dst, online exp + weighted sum ----------
__global__ __launch_bounds__(256) void aggr1_kernel(
    const unsigned* __restrict__ rowstart, const int* __restrict__ csr_src,
    const float* __restrict__ a_src, const float* __restrict__ a_dst,
    const unsigned short* __restrict__ h1b, const float* __restrict__ b1,
    float* __restrict__ h2, int N)
{
    int g = blockIdx.x * 4 + (threadIdx.x >> 6);
    int lane = threadIdx.x & 63;
    if (g >= N) return;
    int h = lane >> 3;
    float ad = a_dst[(size_t)g * 8 + h];
    unsigned k0 = rowstart[g], k1 = rowstart[g + 1];
    float acc0 = 0.f, acc1 = 0.f, acc2 = 0.f, acc3 = 0.f;
    float dn0 = 0.f, dn1 = 0.f, dn2 = 0.f, dn3 = 0.f;
    unsigned k = k0;
    for (; k + 4 <= k1; k += 4) {
        int s0 = csr_src[k],     s1 = csr_src[k + 1];
        int s2 = csr_src[k + 2], s3 = csr_src[k + 3];
        float p0 = __expf(leaky(a_src[(size_t)s0 * 8 + h] + ad));
        float p1 = __expf(leaky(a_src[(size_t)s1 * 8 + h] + ad));
        float p2 = __expf(leaky(a_src[(size_t)s2 * 8 + h] + ad));
        float p3 = __expf(leaky(a_src[(size_t)s3 * 8 + h] + ad));
        acc0 += p0 * bfu(h1b[(size_t)s0 * 64 + lane]); dn0 += p0;
        acc1 += p1 * bfu(h1b[(size_t)s1 * 64 + lane]); dn1 += p1;
        acc2 += p2 * bfu(h1b[(size_t)s2 * 64 + lane]); dn2 += p2;
        acc3 += p3 * bfu(h1b[(size_t)s3 * 64 + lane]); dn3 += p3;
    }
    for (; k < k1; ++k) {
        int s0 = csr_src[k];
        float p0 = __expf(leaky(a_src[(size_t)s0 * 8 + h] + ad));
        acc0 += p0 * bfu(h1b[(size_t)s0 * 64 + lane]); dn0 += p0;
    }
    float den = (dn0 + dn1) + (dn2 + dn3);
    float acc = (acc0 + acc1) + (acc2 + acc3);
    float v = acc / (den + EPS_DEN) + b1[lane];
    h2[(size_t)g * 64 + lane] = v > 0.f ? v : 0.f;
}

// ---------- GEMM2 + attention dots; h3 stored SPLIT: [N,32] (64B rows = 1 line
// per gather) + [N,8] (1.6MB, L2-resident) ----------
__global__ __launch_bounds__(256) void gemm2_kernel(
    const float* __restrict__ h2, const float* __restrict__ W2,
    const float* __restrict__ att_src2, const float* __restrict__ att_dst2,
    unsigned short* __restrict__ h3b32, unsigned short* __restrict__ h3b8,
    float* __restrict__ a_src, float* __restrict__ a_dst, int N)
{
    __shared__ float Wl[64 * 40];
    int t = threadIdx.x;
    for (int i = t; i < 64 * 40; i += 256) Wl[i] = W2[i];
    __syncthreads();
    int lane = t & 63, wy = t >> 6;
    int row = blockIdx.x * 4 + wy;
    if (row >= N) return;
    float acc = 0.f;
    const float* hr = h2 + (size_t)row * 64;
    if (lane < 40) {
#pragma unroll 8
        for (int k = 0; k < 64; ++k) acc += hr[k] * Wl[k * 40 + lane];
        if (lane < 32) h3b32[(size_t)row * 32 + lane] = (unsigned short)bf16rne(acc);
        else           h3b8[(size_t)row * 8 + (lane - 32)] = (unsigned short)bf16rne(acc);
    }
    float ps = (lane < 40) ? acc * att_src2[lane] : 0.f;
    float pd = (lane < 40) ? acc * att_dst2[lane] : 0.f;
#pragma unroll
    for (int off = 32; off; off >>= 1) { ps += __shfl_down(ps, off); pd += __shfl_down(pd, off); }
    if (lane == 0) { a_src[row] = ps; a_dst[row] = pd; }
}

// ---------- L2 fused aggregate: wave per dst, online exp + bias + log_softmax ----------
__global__ __launch_bounds__(256) void aggr2_kernel(
    const unsigned* __restrict__ rowstart, const int* __restrict__ csr_src,
    const float* __restrict__ a_src, const float* __restrict__ a_dst,
    const unsigned short* __restrict__ h3b32, const unsigned short* __restrict__ h3b8,
    const float* __restrict__ b2, float* __restrict__ y, int N)
{
    int g = blockIdx.x * 4 + (threadIdx.x >> 6);
    int lane = threadIdx.x & 63;
    if (g >= N) return;
    // branchless per-lane constant source mapping (no per-edge divergence)
    const bool valid = lane < 40;
    const unsigned short* hsrc = (lane < 32) ? h3b32 : h3b8;
    const int rowmul = (lane < 32) ? 32 : 8;
    const int cidx   = (lane < 32) ? lane : (valid ? lane - 32 : 0);
    float ad = a_dst[g];
    unsigned k0 = rowstart[g], k1 = rowstart[g + 1];
    float acc0 = 0.f, acc1 = 0.f, acc2 = 0.f, acc3 = 0.f;
    float dn0 = 0.f, dn1 = 0.f, dn2 = 0.f, dn3 = 0.f;
    unsigned k = k0;
    for (; k + 4 <= k1; k += 4) {
        int s0 = csr_src[k],     s1 = csr_src[k + 1];
        int s2 = csr_src[k + 2], s3 = csr_src[k + 3];
        float p0 = __expf(leaky(a_src[s0] + ad));
        float p1 = __expf(leaky(a_src[s1] + ad));
        float p2 = __expf(leaky(a_src[s2] + ad));
        float p3 = __expf(leaky(a_src[s3] + ad));
        float hv0 = bfu(hsrc[(size_t)s0 * rowmul + cidx]);
        float hv1 = bfu(hsrc[(size_t)s1 * rowmul + cidx]);
        float hv2 = bfu(hsrc[(size_t)s2 * rowmul + cidx]);
        float hv3 = bfu(hsrc[(size_t)s3 * rowmul + cidx]);
        if (!valid) { hv0 = hv1 = hv2 = hv3 = 0.f; }
        acc0 += p0 * hv0; dn0 += p0;
        acc1 += p1 * hv1; dn1 += p1;
        acc2 += p2 * hv2; dn2 += p2;
        acc3 += p3 * hv3; dn3 += p3;
    }
    for (; k < k1; ++k) {
        int s0 = csr_src[k];
        float p0 = __expf(leaky(a_src[s0] + ad));
        float hv0 = valid ? bfu(hsrc[(size_t)s0 * rowmul + cidx]) : 0.f;
        acc0 += p0 * hv0; dn0 += p0;
    }
    float den = (dn0 + dn1) + (dn2 + dn3);
    float acc = (acc0 + acc1) + (acc2 + acc3);
    float v = valid ? (acc / (den + EPS_DEN) + b2[lane]) : -INFINITY;
    float mx = v;
#pragma unroll
    for (int off = 32; off; off >>= 1) mx = fmaxf(mx, __shfl_down(mx, off));
    mx = __shfl(mx, 0);
    float ex = valid ? expf(v - mx) : 0.f;
    float ss = ex;
#pragma unroll
    for (int off = 32; off; off >>= 1) ss += __shfl_down(ss, off);
    ss = __shfl(ss, 0);
    if (valid) y[(size_t)g * 40 + lane] = v - mx - logf(ss);
}

// ---------- launch ----------
extern "C" void kernel_launch(void* const* d_in, const int* in_sizes, int n_in,
                              void* d_out, int out_size, void* d_ws, size_t ws_size,
                              hipStream_t stream)
{
    const float* x        = (const float*)d_in[0];
    const int*   ei       = (const int*)d_in[1];
    const float* W1       = (const float*)d_in[2];
    const float* att_src1 = (const float*)d_in[3];
    const float* att_dst1 = (const float*)d_in[4];
    const float* b1       = (const float*)d_in[5];
    const float* W2       = (const float*)d_in[6];
    const float* att_src2 = (const float*)d_in[7];
    const float* att_dst2 = (const float*)d_in[8];
    const float* b2       = (const float*)d_in[9];
    float* y = (float*)d_out;

    int N = in_sizes[0] / 512;
    int E = in_sizes[1] / 2;
    int Etot = E + N;
    int nb = (N + 255) / 256;
    int sliceW = (N + 7) / 8;

    char* p = (char*)d_ws;
    unsigned short* h1b = (unsigned short*)p; p += (size_t)N * 64 * 2;
    float* a_src1a  = (float*)p;   p += (size_t)N * 8 * 4;
    float* a_dst1a  = (float*)p;   p += (size_t)N * 8 * 4;
    float* h2       = (float*)p;   p += (size_t)N * 64 * 4;
    unsigned short* h3b32 = (unsigned short*)p; p += (size_t)N * 32 * 2;
    unsigned short* h3b8  = (unsigned short*)p; p += (size_t)N * 8 * 2;
    float* a_src2a  = (float*)p;   p += (size_t)N * 4;
    float* a_dst2a  = (float*)p;   p += (size_t)N * 4;
    unsigned* deg   = (unsigned*)p; p += (size_t)N * 4;
    unsigned* loc   = (unsigned*)p; p += (size_t)N * 4;
    unsigned* bsum  = (unsigned*)p; p += (size_t)nb * 4;
    unsigned* rowstart = (unsigned*)p; p += (size_t)(N + 1) * 4;
    unsigned* cursor   = (unsigned*)p; p += (size_t)N * 4;
    int* csr_src    = (int*)p;     p += (size_t)Etot * 4;

    hipMemsetAsync(deg, 0, (size_t)N * 4, stream);

    // GEMM1 (MFMA) then attention logits
    gemm1_mfma<<<(N + 127) / 128, 256, 0, stream>>>(x, W1, h1b, N);
    att1_kernel<<<(N * 8 + 255) / 256, 256, 0, stream>>>(h1b, att_src1, att_dst1, a_src1a, a_dst1a, N);

    // CSR build (shared by both layers)
    deg_kernel<<<(Etot + 255) / 256, 256, 0, stream>>>(ei, deg, E, Etot);
    scanA_kernel<<<nb, 256, 0, stream>>>(deg, loc, bsum, N);
    scanB_kernel<<<1, 1024, 0, stream>>>(bsum, nb);
    scanC_kernel<<<nb, 256, 0, stream>>>(loc, bsum, rowstart, cursor, N, Etot);
    scatter_kernel<<<8 * ((Etot + 255) / 256), 256, 0, stream>>>(ei, cursor, csr_src, E, Etot, sliceW);

    // L1: fused softmax + aggregate + bias + relu
    aggr1_kernel<<<(N + 3) / 4, 256, 0, stream>>>(rowstart, csr_src, a_src1a, a_dst1a, h1b, b1, h2, N);

    // GEMM2 + attention logits (split h3 layout)
    gemm2_kernel<<<(N + 3) / 4, 256, 0, stream>>>(h2, W2, att_src2, att_dst2, h3b32, h3b8, a_src2a, a_dst2a, N);

    // L2: fused softmax + aggregate + bias + log_softmax
    aggr2_kernel<<<(N + 3) / 4, 256, 0, stream>>>(rowstart, csr_src, a_src2a, a_dst2a, h3b32, h3b8, b2, y, N);
}

// Round 3
// 679.062 us; speedup vs baseline: 1.3234x; 1.0196x over previous
//
#include <hip/hip_runtime.h>
#include <math.h>

#define NEG_SLOPE 0.2f
#define EPS_DEN 1e-16f

__device__ __forceinline__ float leaky(float v) { return v > 0.f ? v : NEG_SLOPE * v; }

typedef __attribute__((ext_vector_type(8))) short bf16x8;
typedef __attribute__((ext_vector_type(4))) float f32x4;

__device__ __forceinline__ unsigned bf16rne(float f) {
    unsigned u = __float_as_uint(f);
    return (u + 0x7FFFu + ((u >> 16) & 1u)) >> 16;
}
// HW packed f32->bf16 RNE convert: 1 instr instead of ~10
__device__ __forceinline__ unsigned pack2(float a, float b) {
    unsigned r;
    asm("v_cvt_pk_bf16_f32 %0, %1, %2" : "=v"(r) : "v"(a), "v"(b));
    return r;
}
__device__ __forceinline__ float bfu(unsigned short u) {
    return __uint_as_float(((unsigned)u) << 16);
}

// ---------- GEMM1 (MFMA) + fused att1: h1b[N,64](bf16) = x@W1; a_src/a_dst dots ----------
__global__ __launch_bounds__(256) void gemm1_mfma(
    const float* __restrict__ x, const float* __restrict__ W1,
    const float* __restrict__ att_src1, const float* __restrict__ att_dst1,
    unsigned short* __restrict__ h1b, float* __restrict__ a_src,
    float* __restrict__ a_dst, int N)
{
    __shared__ __align__(16) unsigned short As[128 * 40];
    __shared__ __align__(16) unsigned short Bs[64 * 40];

    const int t = threadIdx.x;
    const int w = t >> 6;
    const int lane = t & 63;
    const int m16 = lane & 15;
    const int quad = lane >> 4;
    const int rowBase = blockIdx.x * 128;

    f32x4 acc[2][4];
#pragma unroll
    for (int i = 0; i < 2; ++i)
#pragma unroll
        for (int j = 0; j < 4; ++j) acc[i][j] = (f32x4){0.f, 0.f, 0.f, 0.f};

    const float4* x4 = (const float4*)x;

#pragma unroll 1
    for (int chunk = 0; chunk < 16; ++chunk) {
        const int k0 = chunk * 32;
#pragma unroll
        for (int r = 0; r < 4; ++r) {
            int e = t + r * 256;
            int row = e >> 3;
            int kg = e & 7;
            int grow = rowBase + row;
            float4 v = make_float4(0.f, 0.f, 0.f, 0.f);
            if (grow < N) v = x4[(size_t)grow * 128 + (k0 >> 2) + kg];
            uint2 pk = make_uint2(pack2(v.x, v.y), pack2(v.z, v.w));
            *(uint2*)&As[row * 40 + kg * 4] = pk;
        }
        {
            int c = lane;
            int jb = w * 8;
            float f[8];
#pragma unroll
            for (int j = 0; j < 8; ++j) f[j] = W1[(size_t)(k0 + jb + j) * 64 + c];
            uint4 pk;
            pk.x = pack2(f[0], f[1]); pk.y = pack2(f[2], f[3]);
            pk.z = pack2(f[4], f[5]); pk.w = pack2(f[6], f[7]);
            *(uint4*)&Bs[c * 40 + jb] = pk;
        }
        __syncthreads();
        bf16x8 a0 = *(const bf16x8*)&As[(w * 32 + m16) * 40 + quad * 8];
        bf16x8 a1 = *(const bf16x8*)&As[(w * 32 + 16 + m16) * 40 + quad * 8];
#pragma unroll
        for (int j = 0; j < 4; ++j) {
            bf16x8 b = *(const bf16x8*)&Bs[(j * 16 + m16) * 40 + quad * 8];
            acc[0][j] = __builtin_amdgcn_mfma_f32_16x16x32_bf16(a0, b, acc[0][j], 0, 0, 0);
            acc[1][j] = __builtin_amdgcn_mfma_f32_16x16x32_bf16(a1, b, acc[1][j], 0, 0, 0);
        }
        __syncthreads();
    }

    // per-lane att weights for its 4 channels (j*16 + m16)
    float ats[4], atd[4];
#pragma unroll
    for (int j = 0; j < 4; ++j) {
        ats[j] = att_src1[j * 16 + m16];
        atd[j] = att_dst1[j * 16 + m16];
    }

#pragma unroll
    for (int i = 0; i < 2; ++i)
#pragma unroll
        for (int reg = 0; reg < 4; ++reg) {
            int r = rowBase + w * 32 + i * 16 + quad * 4 + reg;
            if (r < N) {
#pragma unroll
                for (int j = 0; j < 4; ++j) {
                    float val = acc[i][j][reg];
                    h1b[(size_t)r * 64 + j * 16 + m16] = (unsigned short)bf16rne(val);
                    // fused attention dots: head = j*2 + (m16>>3); reduce over the
                    // 8-lane subgroup (m16 bits 0..2); whole 16-lane group shares r.
                    float ps = val * ats[j];
                    float pd = val * atd[j];
                    ps += __shfl_xor(ps, 1); pd += __shfl_xor(pd, 1);
                    ps += __shfl_xor(ps, 2); pd += __shfl_xor(pd, 2);
                    ps += __shfl_xor(ps, 4); pd += __shfl_xor(pd, 4);
                    if ((m16 & 7) == 0) {
                        int head = j * 2 + (m16 >> 3);
                        a_src[(size_t)r * 8 + head] = ps;
                        a_dst[(size_t)r * 8 + head] = pd;
                    }
                }
            }
        }
}

// ---------- CSR build ----------
__global__ __launch_bounds__(256) void deg_kernel(
    const int* __restrict__ ei, unsigned* __restrict__ deg, int E, int Etot)
{
    int idx = blockIdx.x * blockDim.x + threadIdx.x;
    if (idx >= Etot) return;
    int d = (idx < E) ? ei[E + idx] : (idx - E);
    atomicAdd(&deg[d], 1u);
}

__global__ __launch_bounds__(256) void scanA_kernel(
    const unsigned* __restrict__ deg, unsigned* __restrict__ loc,
    unsigned* __restrict__ bsum, int N)
{
    __shared__ unsigned sh[256];
    int i = blockIdx.x * 256 + threadIdx.x;
    unsigned v = (i < N) ? deg[i] : 0u;
    sh[threadIdx.x] = v;
    __syncthreads();
    for (int off = 1; off < 256; off <<= 1) {
        unsigned u = (threadIdx.x >= (unsigned)off) ? sh[threadIdx.x - off] : 0u;
        __syncthreads();
        sh[threadIdx.x] += u;
        __syncthreads();
    }
    if (i < N) loc[i] = sh[threadIdx.x] - v;
    if (threadIdx.x == 255) bsum[blockIdx.x] = sh[255];
}

__global__ __launch_bounds__(1024) void scanB_kernel(unsigned* __restrict__ bsum, int nb)
{
    __shared__ unsigned sh[1024];
    int t = threadIdx.x;
    unsigned carry = 0;
    for (int base = 0; base < nb; base += 1024) {
        int i = base + t;
        unsigned v = (i < nb) ? bsum[i] : 0u;
        sh[t] = v;
        __syncthreads();
        for (int off = 1; off < 1024; off <<= 1) {
            unsigned u = (t >= off) ? sh[t - off] : 0u;
            __syncthreads();
            sh[t] += u;
            __syncthreads();
        }
        unsigned incl = sh[t];
        unsigned tot  = sh[1023];
        __syncthreads();
        if (i < nb) bsum[i] = incl - v + carry;
        carry += tot;
        __syncthreads();
    }
}

__global__ __launch_bounds__(256) void scanC_kernel(
    const unsigned* __restrict__ loc, const unsigned* __restrict__ bsum,
    unsigned* __restrict__ rowstart, unsigned* __restrict__ cursor, int N, int Etot)
{
    int i = blockIdx.x * 256 + threadIdx.x;
    if (i >= N) return;
    unsigned r = loc[i] + bsum[blockIdx.x];
    rowstart[i] = r;
    cursor[i] = r;
    if (i == 0) rowstart[N] = (unsigned)Etot;
}

// ---------- XCD-sliced scatter (kills write amplification via per-XCD L2 locality) ----------
__global__ __launch_bounds__(256) void scatter_kernel(
    const int* __restrict__ ei, unsigned* __restrict__ cursor,
    int* __restrict__ csr_src, int E, int Etot, int sliceW)
{
    int slice = blockIdx.x & 7;
    int idx = (blockIdx.x >> 3) * 256 + threadIdx.x;
    if (idx >= Etot) return;
    int d = (idx < E) ? ei[E + idx] : (idx - E);
    int lo = slice * sliceW;
    if (d < lo || d >= lo + sliceW) return;
    int s = (idx < E) ? ei[idx] : d;
    unsigned pos = atomicAdd(&cursor[d], 1u);
    csr_src[pos] = s;
}

// ---------- L1 fused aggregate: wave per dst, 2 edges/wave via half-waves,
// dword gathers (2 bf16 channels per lane) ----------
__global__ __launch_bounds__(256) void aggr1_kernel(
    const unsigned* __restrict__ rowstart, const int* __restrict__ csr_src,
    const float* __restrict__ a_src, const float* __restrict__ a_dst,
    const unsigned short* __restrict__ h1b, const float* __restrict__ b1,
    float* __restrict__ h2, int N)
{
    int g = blockIdx.x * 4 + (threadIdx.x >> 6);
    int lane = threadIdx.x & 63;
    if (g >= N) return;
    int half = lane >> 5;
    int l = lane & 31;            // channel pair: channels 2l, 2l+1
    int h = l >> 2;               // head of both channels
    float ad = a_dst[(size_t)g * 8 + h];
    const unsigned* h1u = (const unsigned*)h1b;
    unsigned k0 = rowstart[g], k1 = rowstart[g + 1];
    float ax0 = 0.f, ay0 = 0.f, ax1 = 0.f, ay1 = 0.f;
    float dn0 = 0.f, dn1 = 0.f;
    unsigned k = k0;
    for (; k + 4 <= k1; k += 4) {
        int e0 = k + half, e1 = k + 2 + half;
        int s0 = csr_src[e0], s1 = csr_src[e1];
        float p0 = __expf(leaky(a_src[(size_t)s0 * 8 + h] + ad));
        float p1 = __expf(leaky(a_src[(size_t)s1 * 8 + h] + ad));
        unsigned v0 = h1u[(size_t)s0 * 32 + l];
        unsigned v1 = h1u[(size_t)s1 * 32 + l];
        ax0 += p0 * bfu((unsigned short)v0); ay0 += p0 * bfu((unsigned short)(v0 >> 16)); dn0 += p0;
        ax1 += p1 * bfu((unsigned short)v1); ay1 += p1 * bfu((unsigned short)(v1 >> 16)); dn1 += p1;
    }
    for (; k < k1; k += 2) {
        unsigned e = k + half;
        if (e < k1) {
            int s = csr_src[e];
            float p = __expf(leaky(a_src[(size_t)s * 8 + h] + ad));
            unsigned v = h1u[(size_t)s * 32 + l];
            ax0 += p * bfu((unsigned short)v); ay0 += p * bfu((unsigned short)(v >> 16)); dn0 += p;
        }
    }
    float ax = ax0 + ax1, ay = ay0 + ay1, dn = dn0 + dn1;
    ax += __shfl_xor(ax, 32);
    ay += __shfl_xor(ay, 32);
    dn += __shfl_xor(dn, 32);
    if (half == 0) {
        float inv = 1.f / (dn + EPS_DEN);
        float vx = ax * inv + b1[2 * l];
        float vy = ay * inv + b1[2 * l + 1];
        float2 o;
        o.x = vx > 0.f ? vx : 0.f;
        o.y = vy > 0.f ? vy : 0.f;
        *(float2*)&h2[(size_t)g * 64 + 2 * l] = o;
    }
}

// ---------- GEMM2 + attention dots; h3 split [N,32]+[N,8] bf16 ----------
__global__ __launch_bounds__(256) void gemm2_kernel(
    const float* __restrict__ h2, const float* __restrict__ W2,
    const float* __restrict__ att_src2, const float* __restrict__ att_dst2,
    unsigned short* __restrict__ h3b32, unsigned short* __restrict__ h3b8,
    float* __restrict__ a_src, float* __restrict__ a_dst, int N)
{
    __shared__ float Wl[64 * 40];
    int t = threadIdx.x;
    for (int i = t; i < 64 * 40; i += 256) Wl[i] = W2[i];
    __syncthreads();
    int lane = t & 63, wy = t >> 6;
    int row = blockIdx.x * 4 + wy;
    if (row >= N) return;
    float acc = 0.f;
    const float* hr = h2 + (size_t)row * 64;
    if (lane < 40) {
#pragma unroll 8
        for (int k = 0; k < 64; ++k) acc += hr[k] * Wl[k * 40 + lane];
        if (lane < 32) h3b32[(size_t)row * 32 + lane] = (unsigned short)bf16rne(acc);
        else           h3b8[(size_t)row * 8 + (lane - 32)] = (unsigned short)bf16rne(acc);
    }
    float ps = (lane < 40) ? acc * att_src2[lane] : 0.f;
    float pd = (lane < 40) ? acc * att_dst2[lane] : 0.f;
#pragma unroll
    for (int off = 32; off; off >>= 1) { ps += __shfl_down(ps, off); pd += __shfl_down(pd, off); }
    if (lane == 0) { a_src[row] = ps; a_dst[row] = pd; }
}

// ---------- L2 fused aggregate: wave per dst, 2 edges/wave, dword gathers,
// fused bias + log_softmax ----------
__global__ __launch_bounds__(256) void aggr2_kernel(
    const unsigned* __restrict__ rowstart, const int* __restrict__ csr_src,
    const float* __restrict__ a_src, const float* __restrict__ a_dst,
    const unsigned short* __restrict__ h3b32, const unsigned short* __restrict__ h3b8,
    const float* __restrict__ b2, float* __restrict__ y, int N)
{
    int g = blockIdx.x * 4 + (threadIdx.x >> 6);
    int lane = threadIdx.x & 63;
    if (g >= N) return;
    int half = lane >> 5;
    int l = lane & 31;            // pair index: channels 2l, 2l+1 (valid l<20)
    const bool valid = l < 20;
    const unsigned* hsrc = (l < 16) ? (const unsigned*)h3b32 : (const unsigned*)h3b8;
    const int rowmul = (l < 16) ? 16 : 4;
    const int cidx   = (l < 16) ? l : (valid ? l - 16 : 0);
    float ad = a_dst[g];
    unsigned k0 = rowstart[g], k1 = rowstart[g + 1];
    float ax0 = 0.f, ay0 = 0.f, ax1 = 0.f, ay1 = 0.f;
    float dn0 = 0.f, dn1 = 0.f;
    unsigned k = k0;
    for (; k + 4 <= k1; k += 4) {
        int e0 = k + half, e1 = k + 2 + half;
        int s0 = csr_src[e0], s1 = csr_src[e1];
        float p0 = __expf(leaky(a_src[s0] + ad));
        float p1 = __expf(leaky(a_src[s1] + ad));
        unsigned v0 = valid ? hsrc[(size_t)s0 * rowmul + cidx] : 0u;
        unsigned v1 = valid ? hsrc[(size_t)s1 * rowmul + cidx] : 0u;
        ax0 += p0 * bfu((unsigned short)v0); ay0 += p0 * bfu((unsigned short)(v0 >> 16)); dn0 += p0;
        ax1 += p1 * bfu((unsigned short)v1); ay1 += p1 * bfu((unsigned short)(v1 >> 16)); dn1 += p1;
    }
    for (; k < k1; k += 2) {
        unsigned e = k + half;
        if (e < k1) {
            int s = csr_src[e];
            float p = __expf(leaky(a_src[s] + ad));
            unsigned v = valid ? hsrc[(size_t)s * rowmul + cidx] : 0u;
            ax0 += p * bfu((unsigned short)v); ay0 += p * bfu((unsigned short)(v >> 16)); dn0 += p;
        }
    }
    float ax = ax0 + ax1, ay = ay0 + ay1, dn = dn0 + dn1;
    ax += __shfl_xor(ax, 32);
    ay += __shfl_xor(ay, 32);
    dn += __shfl_xor(dn, 32);
    float inv = 1.f / (dn + EPS_DEN);
    float vx = valid ? (ax * inv + b2[2 * l]) : -INFINITY;
    float vy = valid ? (ay * inv + b2[2 * l + 1]) : -INFINITY;
    float mx = fmaxf(vx, vy);
#pragma unroll
    for (int off = 16; off; off >>= 1) mx = fmaxf(mx, __shfl_xor(mx, off));
    float ex = valid ? (__expf(vx - mx) + __expf(vy - mx)) : 0.f;
    float ss = ex;
#pragma unroll
    for (int off = 16; off; off >>= 1) ss += __shfl_xor(ss, off);
    float lse = mx + __logf(ss);
    if (half == 0 && valid) {
        float2 o;
        o.x = vx - lse;
        o.y = vy - lse;
        *(float2*)&y[(size_t)g * 40 + 2 * l] = o;
    }
}

// ---------- launch ----------
extern "C" void kernel_launch(void* const* d_in, const int* in_sizes, int n_in,
                              void* d_out, int out_size, void* d_ws, size_t ws_size,
                              hipStream_t stream)
{
    const float* x        = (const float*)d_in[0];
    const int*   ei       = (const int*)d_in[1];
    const float* W1       = (const float*)d_in[2];
    const float* att_src1 = (const float*)d_in[3];
    const float* att_dst1 = (const float*)d_in[4];
    const float* b1       = (const float*)d_in[5];
    const float* W2       = (const float*)d_in[6];
    const float* att_src2 = (const float*)d_in[7];
    const float* att_dst2 = (const float*)d_in[8];
    const float* b2       = (const float*)d_in[9];
    float* y = (float*)d_out;

    int N = in_sizes[0] / 512;
    int E = in_sizes[1] / 2;
    int Etot = E + N;
    int nb = (N + 255) / 256;
    int sliceW = (N + 7) / 8;

    char* p = (char*)d_ws;
    unsigned short* h1b = (unsigned short*)p; p += (size_t)N * 64 * 2;
    float* a_src1a  = (float*)p;   p += (size_t)N * 8 * 4;
    float* a_dst1a  = (float*)p;   p += (size_t)N * 8 * 4;
    float* h2       = (float*)p;   p += (size_t)N * 64 * 4;
    unsigned short* h3b32 = (unsigned short*)p; p += (size_t)N * 32 * 2;
    unsigned short* h3b8  = (unsigned short*)p; p += (size_t)N * 8 * 2;
    float* a_src2a  = (float*)p;   p += (size_t)N * 4;
    float* a_dst2a  = (float*)p;   p += (size_t)N * 4;
    unsigned* deg   = (unsigned*)p; p += (size_t)N * 4;
    unsigned* loc   = (unsigned*)p; p += (size_t)N * 4;
    unsigned* bsum  = (unsigned*)p; p += (size_t)nb * 4;
    unsigned* rowstart = (unsigned*)p; p += (size_t)(N + 1) * 4;
    unsigned* cursor   = (unsigned*)p; p += (size_t)N * 4;
    int* csr_src    = (int*)p;     p += (size_t)Etot * 4;

    hipMemsetAsync(deg, 0, (size_t)N * 4, stream);

    // GEMM1 (MFMA) with fused attention logits
    gemm1_mfma<<<(N + 127) / 128, 256, 0, stream>>>(x, W1, att_src1, att_dst1, h1b, a_src1a, a_dst1a, N);

    // CSR build (shared by both layers)
    deg_kernel<<<(Etot + 255) / 256, 256, 0, stream>>>(ei, deg, E, Etot);
    scanA_kernel<<<nb, 256, 0, stream>>>(deg, loc, bsum, N);
    scanB_kernel<<<1, 1024, 0, stream>>>(bsum, nb);
    scanC_kernel<<<nb, 256, 0, stream>>>(loc, bsum, rowstart, cursor, N, Etot);
    scatter_kernel<<<8 * ((Etot + 255) / 256), 256, 0, stream>>>(ei, cursor, csr_src, E, Etot, sliceW);

    // L1: fused softmax + aggregate + bias + relu
    aggr1_kernel<<<(N + 3) / 4, 256, 0, stream>>>(rowstart, csr_src, a_src1a, a_dst1a, h1b, b1, h2, N);

    // GEMM2 + attention logits (split h3 layout)
    gemm2_kernel<<<(N + 3) / 4, 256, 0, stream>>>(h2, W2, att_src2, att_dst2, h3b32, h3b8, a_src2a, a_dst2a, N);

    // L2: fused softmax + aggregate + bias + log_softmax
    aggr2_kernel<<<(N + 3) / 4, 256, 0, stream>>>(rowstart, csr_src, a_src2a, a_dst2a, h3b32, h3b8, b2, y, N);
}

// Round 5
// 659.203 us; speedup vs baseline: 1.3633x; 1.0301x over previous
//
#include <hip/hip_runtime.h>
#include <math.h>

#define NEG_SLOPE 0.2f
#define EPS_DEN 1e-16f

__device__ __forceinline__ float leaky(float v) { return v > 0.f ? v : NEG_SLOPE * v; }

typedef __attribute__((ext_vector_type(8))) short bf16x8;
typedef __attribute__((ext_vector_type(4))) float f32x4;

__device__ __forceinline__ unsigned bf16rne(float f) {
    unsigned u = __float_as_uint(f);
    return (u + 0x7FFFu + ((u >> 16) & 1u)) >> 16;
}
// HW packed f32->bf16 RNE convert: 1 instr instead of ~10
__device__ __forceinline__ unsigned pack2(float a, float b) {
    unsigned r;
    asm("v_cvt_pk_bf16_f32 %0, %1, %2" : "=v"(r) : "v"(a), "v"(b));
    return r;
}
__device__ __forceinline__ float bfu(unsigned short u) {
    return __uint_as_float(((unsigned)u) << 16);
}

// ---------- GEMM1 (MFMA) + fused att1, register-prefetch pipelined staging ----------
__global__ __launch_bounds__(256) void gemm1_mfma(
    const float* __restrict__ x, const float* __restrict__ W1,
    const float* __restrict__ att_src1, const float* __restrict__ att_dst1,
    unsigned short* __restrict__ h1b, float* __restrict__ a_src,
    float* __restrict__ a_dst, int N)
{
    __shared__ __align__(16) unsigned short As[128 * 40];
    __shared__ __align__(16) unsigned short Bs[64 * 40];

    const int t = threadIdx.x;
    const int w = t >> 6;
    const int lane = t & 63;
    const int m16 = lane & 15;
    const int quad = lane >> 4;
    const int rowBase = blockIdx.x * 128;

    f32x4 acc[2][4];
#pragma unroll
    for (int i = 0; i < 2; ++i)
#pragma unroll
        for (int j = 0; j < 4; ++j) acc[i][j] = (f32x4){0.f, 0.f, 0.f, 0.f};

    const float4* x4 = (const float4*)x;
    const int jb = w * 8;
    const int c = lane;

    // per-thread A-staging coordinates (constant across chunks)
    int arow[4], akg[4], agrow[4];
    bool aok[4];
#pragma unroll
    for (int r = 0; r < 4; ++r) {
        int e = t + r * 256;
        arow[r] = e >> 3;
        akg[r] = e & 7;
        agrow[r] = rowBase + arow[r];
        aok[r] = agrow[r] < N;
    }

    float4 vx[4];
    float wf[8];

    // prologue: load chunk 0
#pragma unroll
    for (int r = 0; r < 4; ++r) {
        vx[r] = make_float4(0.f, 0.f, 0.f, 0.f);
        if (aok[r]) vx[r] = x4[(size_t)agrow[r] * 128 + akg[r]];
    }
#pragma unroll
    for (int j = 0; j < 8; ++j) wf[j] = W1[(size_t)(jb + j) * 64 + c];

#pragma unroll 1
    for (int chunk = 0; chunk < 16; ++chunk) {
        // stage prefetched regs to LDS
#pragma unroll
        for (int r = 0; r < 4; ++r) {
            uint2 pk = make_uint2(pack2(vx[r].x, vx[r].y), pack2(vx[r].z, vx[r].w));
            *(uint2*)&As[arow[r] * 40 + akg[r] * 4] = pk;
        }
        {
            uint4 pk;
            pk.x = pack2(wf[0], wf[1]); pk.y = pack2(wf[2], wf[3]);
            pk.z = pack2(wf[4], wf[5]); pk.w = pack2(wf[6], wf[7]);
            *(uint4*)&Bs[c * 40 + jb] = pk;
        }
        __syncthreads();

        // issue next chunk's global loads early (hidden under ds_read + MFMA)
        if (chunk < 15) {
            const int k0n = (chunk + 1) * 32;
#pragma unroll
            for (int r = 0; r < 4; ++r) {
                if (aok[r]) vx[r] = x4[(size_t)agrow[r] * 128 + (k0n >> 2) + akg[r]];
            }
#pragma unroll
            for (int j = 0; j < 8; ++j) wf[j] = W1[(size_t)(k0n + jb + j) * 64 + c];
        }

        bf16x8 a0 = *(const bf16x8*)&As[(w * 32 + m16) * 40 + quad * 8];
        bf16x8 a1 = *(const bf16x8*)&As[(w * 32 + 16 + m16) * 40 + quad * 8];
#pragma unroll
        for (int j = 0; j < 4; ++j) {
            bf16x8 b = *(const bf16x8*)&Bs[(j * 16 + m16) * 40 + quad * 8];
            acc[0][j] = __builtin_amdgcn_mfma_f32_16x16x32_bf16(a0, b, acc[0][j], 0, 0, 0);
            acc[1][j] = __builtin_amdgcn_mfma_f32_16x16x32_bf16(a1, b, acc[1][j], 0, 0, 0);
        }
        __syncthreads();
    }

    // per-lane att weights for its 4 channels (j*16 + m16)
    float ats[4], atd[4];
#pragma unroll
    for (int j = 0; j < 4; ++j) {
        ats[j] = att_src1[j * 16 + m16];
        atd[j] = att_dst1[j * 16 + m16];
    }

#pragma unroll
    for (int i = 0; i < 2; ++i)
#pragma unroll
        for (int reg = 0; reg < 4; ++reg) {
            int r = rowBase + w * 32 + i * 16 + quad * 4 + reg;
            if (r < N) {
#pragma unroll
                for (int j = 0; j < 4; ++j) {
                    float val = acc[i][j][reg];
                    h1b[(size_t)r * 64 + j * 16 + m16] = (unsigned short)bf16rne(val);
                    float ps = val * ats[j];
                    float pd = val * atd[j];
                    ps += __shfl_xor(ps, 1); pd += __shfl_xor(pd, 1);
                    ps += __shfl_xor(ps, 2); pd += __shfl_xor(pd, 2);
                    ps += __shfl_xor(ps, 4); pd += __shfl_xor(pd, 4);
                    if ((m16 & 7) == 0) {
                        int head = j * 2 + (m16 >> 3);
                        a_src[(size_t)r * 8 + head] = ps;
                        a_dst[(size_t)r * 8 + head] = pd;
                    }
                }
            }
        }
}

// ---------- CSR build ----------
__global__ __launch_bounds__(256) void deg_kernel(
    const int* __restrict__ ei, unsigned* __restrict__ deg, int E, int Etot)
{
    int idx = blockIdx.x * blockDim.x + threadIdx.x;
    if (idx >= Etot) return;
    int d = (idx < E) ? ei[E + idx] : (idx - E);
    atomicAdd(&deg[d], 1u);
}

__global__ __launch_bounds__(256) void scanA_kernel(
    const unsigned* __restrict__ deg, unsigned* __restrict__ loc,
    unsigned* __restrict__ bsum, int N)
{
    __shared__ unsigned sh[256];
    int i = blockIdx.x * 256 + threadIdx.x;
    unsigned v = (i < N) ? deg[i] : 0u;
    sh[threadIdx.x] = v;
    __syncthreads();
    for (int off = 1; off < 256; off <<= 1) {
        unsigned u = (threadIdx.x >= (unsigned)off) ? sh[threadIdx.x - off] : 0u;
        __syncthreads();
        sh[threadIdx.x] += u;
        __syncthreads();
    }
    if (i < N) loc[i] = sh[threadIdx.x] - v;
    if (threadIdx.x == 255) bsum[blockIdx.x] = sh[255];
}

__global__ __launch_bounds__(1024) void scanB_kernel(unsigned* __restrict__ bsum, int nb)
{
    __shared__ unsigned sh[1024];
    int t = threadIdx.x;
    unsigned carry = 0;
    for (int base = 0; base < nb; base += 1024) {
        int i = base + t;
        unsigned v = (i < nb) ? bsum[i] : 0u;
        sh[t] = v;
        __syncthreads();
        for (int off = 1; off < 1024; off <<= 1) {
            unsigned u = (t >= off) ? sh[t - off] : 0u;
            __syncthreads();
            sh[t] += u;
            __syncthreads();
        }
        unsigned incl = sh[t];
        unsigned tot  = sh[1023];
        __syncthreads();
        if (i < nb) bsum[i] = incl - v + carry;
        carry += tot;
        __syncthreads();
    }
}

__global__ __launch_bounds__(256) void scanC_kernel(
    const unsigned* __restrict__ loc, const unsigned* __restrict__ bsum,
    unsigned* __restrict__ rowstart, unsigned* __restrict__ cursor, int N, int Etot)
{
    int i = blockIdx.x * 256 + threadIdx.x;
    if (i >= N) return;
    unsigned r = loc[i] + bsum[blockIdx.x];
    rowstart[i] = r;
    cursor[i] = r;
    if (i == 0) rowstart[N] = (unsigned)Etot;
}

// ---------- XCD-sliced scatter (kills write amplification via per-XCD L2 locality) ----------
__global__ __launch_bounds__(256) void scatter_kernel(
    const int* __restrict__ ei, unsigned* __restrict__ cursor,
    int* __restrict__ csr_src, int E, int Etot, int sliceW)
{
    int slice = blockIdx.x & 7;
    int idx = (blockIdx.x >> 3) * 256 + threadIdx.x;
    if (idx >= Etot) return;
    int d = (idx < E) ? ei[E + idx] : (idx - E);
    int lo = slice * sliceW;
    if (d < lo || d >= lo + sliceW) return;
    int s = (idx < E) ? ei[idx] : d;
    unsigned pos = atomicAdd(&cursor[d], 1u);
    csr_src[pos] = s;
}

// ---------- L1 fused aggregate: wave per dst, 8 edges in flight (4 per half-wave),
// dword gathers (2 bf16 channels per lane) ----------
__global__ __launch_bounds__(256) void aggr1_kernel(
    const unsigned* __restrict__ rowstart, const int* __restrict__ csr_src,
    const float* __restrict__ a_src, const float* __restrict__ a_dst,
    const unsigned short* __restrict__ h1b, const float* __restrict__ b1,
    float* __restrict__ h2, int N)
{
    int g = blockIdx.x * 4 + (threadIdx.x >> 6);
    int lane = threadIdx.x & 63;
    if (g >= N) return;
    int half = lane >> 5;
    int l = lane & 31;            // channel pair: channels 2l, 2l+1
    int h = l >> 2;               // head of both channels
    float ad = a_dst[(size_t)g * 8 + h];
    const unsigned* h1u = (const unsigned*)h1b;
    unsigned k0 = rowstart[g], k1 = rowstart[g + 1];
    float ax0 = 0.f, ay0 = 0.f, ax1 = 0.f, ay1 = 0.f;
    float ax2 = 0.f, ay2 = 0.f, ax3 = 0.f, ay3 = 0.f;
    float dn0 = 0.f, dn1 = 0.f, dn2 = 0.f, dn3 = 0.f;
    unsigned k = k0;
    for (; k + 8 <= k1; k += 8) {
        int s0 = csr_src[k + half];
        int s1 = csr_src[k + 2 + half];
        int s2 = csr_src[k + 4 + half];
        int s3 = csr_src[k + 6 + half];
        float p0 = __expf(leaky(a_src[(unsigned)s0 * 8u + h] + ad));
        float p1 = __expf(leaky(a_src[(unsigned)s1 * 8u + h] + ad));
        float p2 = __expf(leaky(a_src[(unsigned)s2 * 8u + h] + ad));
        float p3 = __expf(leaky(a_src[(unsigned)s3 * 8u + h] + ad));
        unsigned v0 = h1u[(unsigned)s0 * 32u + l];
        unsigned v1 = h1u[(unsigned)s1 * 32u + l];
        unsigned v2 = h1u[(unsigned)s2 * 32u + l];
        unsigned v3 = h1u[(unsigned)s3 * 32u + l];
        ax0 += p0 * bfu((unsigned short)v0); ay0 += p0 * bfu((unsigned short)(v0 >> 16)); dn0 += p0;
        ax1 += p1 * bfu((unsigned short)v1); ay1 += p1 * bfu((unsigned short)(v1 >> 16)); dn1 += p1;
        ax2 += p2 * bfu((unsigned short)v2); ay2 += p2 * bfu((unsigned short)(v2 >> 16)); dn2 += p2;
        ax3 += p3 * bfu((unsigned short)v3); ay3 += p3 * bfu((unsigned short)(v3 >> 16)); dn3 += p3;
    }
    for (; k + 4 <= k1; k += 4) {
        int s0 = csr_src[k + half];
        int s1 = csr_src[k + 2 + half];
        float p0 = __expf(leaky(a_src[(unsigned)s0 * 8u + h] + ad));
        float p1 = __expf(leaky(a_src[(unsigned)s1 * 8u + h] + ad));
        unsigned v0 = h1u[(unsigned)s0 * 32u + l];
        unsigned v1 = h1u[(unsigned)s1 * 32u + l];
        ax0 += p0 * bfu((unsigned short)v0); ay0 += p0 * bfu((unsigned short)(v0 >> 16)); dn0 += p0;
        ax1 += p1 * bfu((unsigned short)v1); ay1 += p1 * bfu((unsigned short)(v1 >> 16)); dn1 += p1;
    }
    for (; k < k1; k += 2) {
        unsigned e = k + half;
        if (e < k1) {
            int s = csr_src[e];
            float p = __expf(leaky(a_src[(unsigned)s * 8u + h] + ad));
            unsigned v = h1u[(unsigned)s * 32u + l];
            ax0 += p * bfu((unsigned short)v); ay0 += p * bfu((unsigned short)(v >> 16)); dn0 += p;
        }
    }
    float ax = (ax0 + ax1) + (ax2 + ax3);
    float ay = (ay0 + ay1) + (ay2 + ay3);
    float dn = (dn0 + dn1) + (dn2 + dn3);
    ax += __shfl_xor(ax, 32);
    ay += __shfl_xor(ay, 32);
    dn += __shfl_xor(dn, 32);
    if (half == 0) {
        float inv = 1.f / (dn + EPS_DEN);
        float vx = ax * inv + b1[2 * l];
        float vy = ay * inv + b1[2 * l + 1];
        float2 o;
        o.x = vx > 0.f ? vx : 0.f;
        o.y = vy > 0.f ? vy : 0.f;
        *(float2*)&h2[(size_t)g * 64 + 2 * l] = o;
    }
}

// ---------- GEMM2 + attention dots; h3 split [N,32]+[N,8] bf16 ----------
__global__ __launch_bounds__(256) void gemm2_kernel(
    const float* __restrict__ h2, const float* __restrict__ W2,
    const float* __restrict__ att_src2, const float* __restrict__ att_dst2,
    unsigned short* __restrict__ h3b32, unsigned short* __restrict__ h3b8,
    float* __restrict__ a_src, float* __restrict__ a_dst, int N)
{
    __shared__ float Wl[64 * 40];
    int t = threadIdx.x;
    for (int i = t; i < 64 * 40; i += 256) Wl[i] = W2[i];
    __syncthreads();
    int lane = t & 63, wy = t >> 6;
    int row = blockIdx.x * 4 + wy;
    if (row >= N) return;
    float acc = 0.f;
    const float* hr = h2 + (size_t)row * 64;
    if (lane < 40) {
#pragma unroll 8
        for (int k = 0; k < 64; ++k) acc += hr[k] * Wl[k * 40 + lane];
        if (lane < 32) h3b32[(size_t)row * 32 + lane] = (unsigned short)bf16rne(acc);
        else           h3b8[(size_t)row * 8 + (lane - 32)] = (unsigned short)bf16rne(acc);
    }
    float ps = (lane < 40) ? acc * att_src2[lane] : 0.f;
    float pd = (lane < 40) ? acc * att_dst2[lane] : 0.f;
#pragma unroll
    for (int off = 32; off; off >>= 1) { ps += __shfl_down(ps, off); pd += __shfl_down(pd, off); }
    if (lane == 0) { a_src[row] = ps; a_dst[row] = pd; }
}

// ---------- L2 fused aggregate: wave per dst, 8 edges in flight, dword gathers,
// fused bias + log_softmax ----------
__global__ __launch_bounds__(256) void aggr2_kernel(
    const unsigned* __restrict__ rowstart, const int* __restrict__ csr_src,
    const float* __restrict__ a_src, const float* __restrict__ a_dst,
    const unsigned short* __restrict__ h3b32, const unsigned short* __restrict__ h3b8,
    const float* __restrict__ b2, float* __restrict__ y, int N)
{
    int g = blockIdx.x * 4 + (threadIdx.x >> 6);
    int lane = threadIdx.x & 63;
    if (g >= N) return;
    int half = lane >> 5;
    int l = lane & 31;            // pair index: channels 2l, 2l+1 (valid l<20)
    const bool valid = l < 20;
    const unsigned* hsrc = (l < 16) ? (const unsigned*)h3b32 : (const unsigned*)h3b8;
    const unsigned rowmul = (l < 16) ? 16u : 4u;
    const unsigned cidx   = (l < 16) ? (unsigned)l : (valid ? (unsigned)(l - 16) : 0u);
    float ad = a_dst[g];
    unsigned k0 = rowstart[g], k1 = rowstart[g + 1];
    float ax0 = 0.f, ay0 = 0.f, ax1 = 0.f, ay1 = 0.f;
    float ax2 = 0.f, ay2 = 0.f, ax3 = 0.f, ay3 = 0.f;
    float dn0 = 0.f, dn1 = 0.f, dn2 = 0.f, dn3 = 0.f;
    unsigned k = k0;
    for (; k + 8 <= k1; k += 8) {
        int s0 = csr_src[k + half];
        int s1 = csr_src[k + 2 + half];
        int s2 = csr_src[k + 4 + half];
        int s3 = csr_src[k + 6 + half];
        float p0 = __expf(leaky(a_src[s0] + ad));
        float p1 = __expf(leaky(a_src[s1] + ad));
        float p2 = __expf(leaky(a_src[s2] + ad));
        float p3 = __expf(leaky(a_src[s3] + ad));
        unsigned v0 = valid ? hsrc[(unsigned)s0 * rowmul + cidx] : 0u;
        unsigned v1 = valid ? hsrc[(unsigned)s1 * rowmul + cidx] : 0u;
        unsigned v2 = valid ? hsrc[(unsigned)s2 * rowmul + cidx] : 0u;
        unsigned v3 = valid ? hsrc[(unsigned)s3 * rowmul + cidx] : 0u;
        ax0 += p0 * bfu((unsigned short)v0); ay0 += p0 * bfu((unsigned short)(v0 >> 16)); dn0 += p0;
        ax1 += p1 * bfu((unsigned short)v1); ay1 += p1 * bfu((unsigned short)(v1 >> 16)); dn1 += p1;
        ax2 += p2 * bfu((unsigned short)v2); ay2 += p2 * bfu((unsigned short)(v2 >> 16)); dn2 += p2;
        ax3 += p3 * bfu((unsigned short)v3); ay3 += p3 * bfu((unsigned short)(v3 >> 16)); dn3 += p3;
    }
    for (; k + 4 <= k1; k += 4) {
        int s0 = csr_src[k + half];
        int s1 = csr_src[k + 2 + half];
        float p0 = __expf(leaky(a_src[s0] + ad));
        float p1 = __expf(leaky(a_src[s1] + ad));
        unsigned v0 = valid ? hsrc[(unsigned)s0 * rowmul + cidx] : 0u;
        unsigned v1 = valid ? hsrc[(unsigned)s1 * rowmul + cidx] : 0u;
        ax0 += p0 * bfu((unsigned short)v0); ay0 += p0 * bfu((unsigned short)(v0 >> 16)); dn0 += p0;
        ax1 += p1 * bfu((unsigned short)v1); ay1 += p1 * bfu((unsigned short)(v1 >> 16)); dn1 += p1;
    }
    for (; k < k1; k += 2) {
        unsigned e = k + half;
        if (e < k1) {
            int s = csr_src[e];
            float p = __expf(leaky(a_src[s] + ad));
            unsigned v = valid ? hsrc[(unsigned)s * rowmul + cidx] : 0u;
            ax0 += p * bfu((unsigned short)v); ay0 += p * bfu((unsigned short)(v >> 16)); dn0 += p;
        }
    }
    float ax = (ax0 + ax1) + (ax2 + ax3);
    float ay = (ay0 + ay1) + (ay2 + ay3);
    float dn = (dn0 + dn1) + (dn2 + dn3);
    ax += __shfl_xor(ax, 32);
    ay += __shfl_xor(ay, 32);
    dn += __shfl_xor(dn, 32);
    float inv = 1.f / (dn + EPS_DEN);
    float vx = valid ? (ax * inv + b2[2 * l]) : -INFINITY;
    float vy = valid ? (ay * inv + b2[2 * l + 1]) : -INFINITY;
    float mx = fmaxf(vx, vy);
#pragma unroll
    for (int off = 16; off; off >>= 1) mx = fmaxf(mx, __shfl_xor(mx, off));
    float ex = valid ? (__expf(vx - mx) + __expf(vy - mx)) : 0.f;
    float ss = ex;
#pragma unroll
    for (int off = 16; off; off >>= 1) ss += __shfl_xor(ss, off);
    float lse = mx + __logf(ss);
    if (half == 0 && valid) {
        float2 o;
        o.x = vx - lse;
        o.y = vy - lse;
        *(float2*)&y[(size_t)g * 40 + 2 * l] = o;
    }
}

// ---------- launch ----------
extern "C" void kernel_launch(void* const* d_in, const int* in_sizes, int n_in,
                              void* d_out, int out_size, void* d_ws, size_t ws_size,
                              hipStream_t stream)
{
    const float* x        = (const float*)d_in[0];
    const int*   ei       = (const int*)d_in[1];
    const float* W1       = (const float*)d_in[2];
    const float* att_src1 = (const float*)d_in[3];
    const float* att_dst1 = (const float*)d_in[4];
    const float* b1       = (const float*)d_in[5];
    const float* W2       = (const float*)d_in[6];
    const float* att_src2 = (const float*)d_in[7];
    const float* att_dst2 = (const float*)d_in[8];
    const float* b2       = (const float*)d_in[9];
    float* y = (float*)d_out;

    int N = in_sizes[0] / 512;
    int E = in_sizes[1] / 2;
    int Etot = E + N;
    int nb = (N + 255) / 256;
    int sliceW = (N + 7) / 8;

    char* p = (char*)d_ws;
    unsigned short* h1b = (unsigned short*)p; p += (size_t)N * 64 * 2;
    float* a_src1a  = (float*)p;   p += (size_t)N * 8 * 4;
    float* a_dst1a  = (float*)p;   p += (size_t)N * 8 * 4;
    float* h2       = (float*)p;   p += (size_t)N * 64 * 4;
    unsigned short* h3b32 = (unsigned short*)p; p += (size_t)N * 32 * 2;
    unsigned short* h3b8  = (unsigned short*)p; p += (size_t)N * 8 * 2;
    float* a_src2a  = (float*)p;   p += (size_t)N * 4;
    float* a_dst2a  = (float*)p;   p += (size_t)N * 4;
    unsigned* deg   = (unsigned*)p; p += (size_t)N * 4;
    unsigned* loc   = (unsigned*)p; p += (size_t)N * 4;
    unsigned* bsum  = (unsigned*)p; p += (size_t)nb * 4;
    unsigned* rowstart = (unsigned*)p; p += (size_t)(N + 1) * 4;
    unsigned* cursor   = (unsigned*)p; p += (size_t)N * 4;
    int* csr_src    = (int*)p;     p += (size_t)Etot * 4;

    hipMemsetAsync(deg, 0, (size_t)N * 4, stream);

    // GEMM1 (MFMA) with fused attention logits
    gemm1_mfma<<<(N + 127) / 128, 256, 0, stream>>>(x, W1, att_src1, att_dst1, h1b, a_src1a, a_dst1a, N);

    // CSR build (shared by both layers)
    deg_kernel<<<(Etot + 255) / 256, 256, 0, stream>>>(ei, deg, E, Etot);
    scanA_kernel<<<nb, 256, 0, stream>>>(deg, loc, bsum, N);
    scanB_kernel<<<1, 1024, 0, stream>>>(bsum, nb);
    scanC_kernel<<<nb, 256, 0, stream>>>(loc, bsum, rowstart, cursor, N, Etot);
    scatter_kernel<<<8 * ((Etot + 255) / 256), 256, 0, stream>>>(ei, cursor, csr_src, E, Etot, sliceW);

    // L1: fused softmax + aggregate + bias + relu
    aggr1_kernel<<<(N + 3) / 4, 256, 0, stream>>>(rowstart, csr_src, a_src1a, a_dst1a, h1b, b1, h2, N);

    // GEMM2 + attention logits (split h3 layout)
    gemm2_kernel<<<(N + 3) / 4, 256, 0, stream>>>(h2, W2, att_src2, att_dst2, h3b32, h3b8, a_src2a, a_dst2a, N);

    // L2: fused softmax + aggregate + bias + log_softmax
    aggr2_kernel<<<(N + 3) / 4, 256, 0, stream>>>(rowstart, csr_src, a_src2a, a_dst2a, h3b32, h3b8, b2, y, N);
}